// Round 13
// baseline (314.004 us; speedup 1.0000x reference)
//
#include <hip/hip_runtime.h>
#include <hip/hip_fp16.h>
#include <math.h>

#define N_NODES 100000
#define N_EDGES 1600000
#define F 128
#define NBUK 196        // ceil(N_NODES / 512)
#define BSH 9           // bucket = node >> 9  (512 nodes per bucket)
#define BSZ 512
#define CAP 10240       // padded bucket capacity (pad-to-4 mean ~8930, sd ~93)
#define NPART 784       // partition blocks (chunk 2044 -> exactly 1 int4 group/thread)
#define PST  1600016    // hA panel stride in fp16 elems: (N_NODES+1)*16
#define PS2  1600000    // h2 panel stride in fp16 elems: N_NODES*16

typedef _Float16 half8 __attribute__((ext_vector_type(8)));
typedef float    f32x4 __attribute__((ext_vector_type(4)));
typedef int      i32x4 __attribute__((ext_vector_type(4)));

// ---------------------------------------------------------------- K1: cursors + hMsg pad row + pack W1/W2
// blocks: 0 = cursors/pad, 1..128 = weight pack
// NOTE: hA pad entries are zeroed in gather_gemm2 (NOT here) — hA aliases bukD/bukS,
// which are still live until csr_gemm1 completes (round-12 lesson).
__global__ __launch_bounds__(256) void init_pack(int* __restrict__ curD,
                                                 int* __restrict__ curS,
                                                 _Float16* __restrict__ padrow1,   // hMsg + N*F (row-major)
                                                 const float* __restrict__ W1,
                                                 const float* __restrict__ W2,
                                                 _Float16* __restrict__ hi1,
                                                 _Float16* __restrict__ lo1,
                                                 _Float16* __restrict__ hi2,
                                                 _Float16* __restrict__ lo2)
{
    int t = threadIdx.x;
    if (blockIdx.x == 0) {
        if (t < NBUK) { curD[t] = t * CAP; curS[t] = t * CAP; }
        if (t < 16) reinterpret_cast<int4*>(padrow1)[t] = make_int4(0, 0, 0, 0);
        return;
    }
    int gidx = (blockIdx.x - 1) * 256 + t;
    const float* W = (gidx < 16384) ? W1 : W2;
    _Float16* hi = (gidx < 16384) ? hi1 : hi2;
    _Float16* lo = (gidx < 16384) ? lo1 : lo2;
    int idx = gidx & 16383;
    int f = idx >> 9, r = idx & 511;
    int l = r >> 3, j = r & 7;
    int kc = f >> 3, ct = f & 7;
    int k = kc * 32 + (l >> 4) * 8 + j;
    int n = ct * 16 + (l & 15);
    float w = W[k * 128 + n];
    _Float16 h = (_Float16)w;
    hi[idx] = h;
    lo[idx] = (_Float16)(w - (float)h);
}

// ---------------------------------------------------------------- K2: partition only (784 blocks, 1 int4 group/thread,
// edges held in registers across both phases)
__global__ __launch_bounds__(512) void part_edges(const int* __restrict__ src,
                                                  const int* __restrict__ dst,
                                                  int* __restrict__ curD,
                                                  int* __restrict__ curS,
                                                  int* __restrict__ bukD,
                                                  unsigned short* __restrict__ bukS)
{
    __shared__ int hd[NBUK], hs[NBUK], bd[NBUK], bs[NBUK], cd[NBUK], cs[NBUK];
    const int tid = threadIdx.x;
    const int chunk = (((N_EDGES + NPART - 1) / NPART) + 3) & ~3;   // 2044
    const int beg = blockIdx.x * chunk;
    const int end = min(beg + chunk, N_EDGES);
    if (beg >= end) return;
    if (tid < NBUK) { hd[tid] = 0; hs[tid] = 0; cd[tid] = 0; cs[tid] = 0; }
    __syncthreads();
    const int b4 = beg >> 2, e4 = end >> 2;
    const int i0 = b4 + tid;                       // exactly <=1 int4 group per thread
    const bool v0 = i0 < e4;
    i32x4 d0 = {}, s0 = {};
    if (v0) {
        d0 = reinterpret_cast<const i32x4*>(dst)[i0];
        s0 = reinterpret_cast<const i32x4*>(src)[i0];
        atomicAdd(&hd[d0.x >> BSH], 1); atomicAdd(&hd[d0.y >> BSH], 1);
        atomicAdd(&hd[d0.z >> BSH], 1); atomicAdd(&hd[d0.w >> BSH], 1);
        atomicAdd(&hs[s0.x >> BSH], 1); atomicAdd(&hs[s0.y >> BSH], 1);
        atomicAdd(&hs[s0.z >> BSH], 1); atomicAdd(&hs[s0.w >> BSH], 1);
    }
    __syncthreads();
    if (tid < NBUK) {
        bd[tid] = hd[tid] ? atomicAdd(&curD[tid], hd[tid]) : 0;
        bs[tid] = hs[tid] ? atomicAdd(&curS[tid], hs[tid]) : 0;
    }
    __syncthreads();
    if (v0) {
        int dd[4] = { d0.x, d0.y, d0.z, d0.w };
        int ss[4] = { s0.x, s0.y, s0.z, s0.w };
        #pragma unroll
        for (int j = 0; j < 4; j++) {
            int bin = dd[j] >> BSH;
            int r = atomicAdd(&cd[bin], 1);
            bukD[bd[bin] + r] = ((dd[j] & 511) << 17) | ss[j];
            int bin2 = ss[j] >> BSH;
            int r2 = atomicAdd(&cs[bin2], 1);
            bukS[bs[bin2] + r2] = (unsigned short)(ss[j] & 511);
        }
    }
}

// ---------------------------------------------------------------- K3: out-degree -> sout (196 blocks, uint4 = 8 entries/load)
__global__ __launch_bounds__(512) void deg_out(const unsigned short* __restrict__ bukS,
                                               const int* __restrict__ curS,
                                               float* __restrict__ sout)
{
    __shared__ int h[BSZ];
    const int tid = threadIdx.x;
    const int n0 = blockIdx.x << BSH;
    const int lo = blockIdx.x * CAP, hi = curS[blockIdx.x];
    const int cnt = hi - lo;
    h[tid] = 0;
    __syncthreads();
    const uint4* p8 = reinterpret_cast<const uint4*>(bukS + lo);   // 16B-aligned (CAP*2 % 16 == 0)
    const int nv = cnt >> 3;
    for (int j = tid; j < nv; j += 512) {
        uint4 v = p8[j];
        atomicAdd(&h[v.x & 0xFFFF], 1); atomicAdd(&h[v.x >> 16], 1);
        atomicAdd(&h[v.y & 0xFFFF], 1); atomicAdd(&h[v.y >> 16], 1);
        atomicAdd(&h[v.z & 0xFFFF], 1); atomicAdd(&h[v.z >> 16], 1);
        atomicAdd(&h[v.w & 0xFFFF], 1); atomicAdd(&h[v.w >> 16], 1);
    }
    for (int i = lo + (nv << 3) + tid; i < hi; i += 512)
        atomicAdd(&h[bukS[i]], 1);
    __syncthreads();
    int node = n0 + tid;
    if (node < N_NODES) sout[node] = rsqrtf((float)max(h[tid], 1));
}

// ---------------------------------------------------------------- K4: csr (196 blocks, col only) + gemm1 scaled by sout (391 blocks)
__global__ __launch_bounds__(512) void csr_gemm1(const int* __restrict__ bukD,
                                                 const int* __restrict__ curD,
                                                 int* __restrict__ row_ptr,
                                                 float* __restrict__ sin_,
                                                 int* __restrict__ col,
                                                 const float* __restrict__ X,
                                                 const _Float16* __restrict__ Whi,
                                                 const _Float16* __restrict__ Wlo,
                                                 const float* __restrict__ sout,
                                                 _Float16* __restrict__ Y, int N)
{
    __shared__ int h[BSZ], sc[BSZ], cur[BSZ];
    const int tid = threadIdx.x;

    if (blockIdx.x < NBUK) {
        const int n0 = blockIdx.x << BSH;
        const int lo = blockIdx.x * CAP, hi = curD[blockIdx.x];
        const int cnt = hi - lo;
        h[tid] = 0;
        __syncthreads();
        const i32x4* p4 = reinterpret_cast<const i32x4*>(bukD + lo);   // 16B-aligned (CAP % 4 == 0)
        const int nv = cnt >> 2;
        for (int j = tid; j < nv; j += 512) {
            i32x4 v = p4[j];
            atomicAdd(&h[((unsigned)v.x) >> 17], 1);
            atomicAdd(&h[((unsigned)v.y) >> 17], 1);
            atomicAdd(&h[((unsigned)v.z) >> 17], 1);
            atomicAdd(&h[((unsigned)v.w) >> 17], 1);
        }
        for (int i = lo + (nv << 2) + tid; i < hi; i += 512)
            atomicAdd(&h[((unsigned)bukD[i]) >> 17], 1);
        __syncthreads();
        int own = h[tid];
        int own4 = (own + 3) & ~3;
        sc[tid] = own4;
        __syncthreads();
        for (int off = 1; off < 512; off <<= 1) {
            int u = (tid >= off) ? sc[tid - off] : 0;
            __syncthreads();
            sc[tid] += u;
            __syncthreads();
        }
        int ex = sc[tid] - own4;
        cur[tid] = ex;
        int node = n0 + tid;
        if (node < N_NODES) {
            row_ptr[2 * node]     = lo + ex;
            row_ptr[2 * node + 1] = lo + ex + own4;          // padded end
            sin_[node] = rsqrtf((float)max(own, 1));
        }
        __syncthreads();
        for (int j = tid; j < nv; j += 512) {
            i32x4 v = p4[j];
            int pv[4] = { v.x, v.y, v.z, v.w };
            #pragma unroll
            for (int q = 0; q < 4; q++) {
                int p = pv[q];
                int r = atomicAdd(&cur[((unsigned)p) >> 17], 1);
                col[lo + r] = p & 0x1FFFF;
            }
        }
        for (int i = lo + (nv << 2) + tid; i < hi; i += 512) {
            int p = bukD[i];
            int r = atomicAdd(&cur[((unsigned)p) >> 17], 1);
            col[lo + r] = p & 0x1FFFF;
        }
        for (int k = own; k < own4; k++)
            col[lo + ex + k] = N_NODES;   // zero row of hMsg / pad entry of hA panels
        return;
    }

    // ---------------- gemm1: sout-folded output (row-major hMsg) ----------------
    const int l = tid & 63, w = tid >> 6;
    const int quad = l >> 4, m = l & 15;
    const int row0 = (blockIdx.x - NBUK) * 256;
    const half8* Bh = reinterpret_cast<const half8*>(Whi);
    const half8* Bl = reinterpret_cast<const half8*>(Wlo);

    f32x4 acc[2][8] = {};

    for (int kc = 0; kc < 4; kc++) {
        half8 ah[2];
        #pragma unroll
        for (int rt = 0; rt < 2; rt++) {
            int grow = row0 + w * 32 + rt * 16 + m;
            float4 xa = make_float4(0.f, 0.f, 0.f, 0.f), xb = xa;
            if (grow < N) {
                const float4* Xp = reinterpret_cast<const float4*>(X) + (size_t)grow * 32 + kc * 8 + quad * 2;
                xa = Xp[0]; xb = Xp[1];
            }
            ah[rt][0] = (_Float16)xa.x; ah[rt][1] = (_Float16)xa.y;
            ah[rt][2] = (_Float16)xa.z; ah[rt][3] = (_Float16)xa.w;
            ah[rt][4] = (_Float16)xb.x; ah[rt][5] = (_Float16)xb.y;
            ah[rt][6] = (_Float16)xb.z; ah[rt][7] = (_Float16)xb.w;
        }
        #pragma unroll
        for (int ct = 0; ct < 8; ct++) {
            int f = kc * 8 + ct;
            half8 bh = Bh[f * 64 + l];
            half8 bl = Bl[f * 64 + l];
            #pragma unroll
            for (int rt = 0; rt < 2; rt++) {
                acc[rt][ct] = __builtin_amdgcn_mfma_f32_16x16x32_f16(ah[rt], bh, acc[rt][ct], 0, 0, 0);
                acc[rt][ct] = __builtin_amdgcn_mfma_f32_16x16x32_f16(ah[rt], bl, acc[rt][ct], 0, 0, 0);
            }
        }
    }

    #pragma unroll
    for (int rt = 0; rt < 2; rt++) {
        #pragma unroll
        for (int r = 0; r < 4; r++) {
            int grow = row0 + w * 32 + rt * 16 + quad * 4 + r;
            if (grow < N) {
                float s = sout[grow];
                #pragma unroll
                for (int ct = 0; ct < 8; ct++)
                    Y[(size_t)grow * 128 + ct * 16 + m] = (_Float16)(acc[rt][ct][r] * s);
            }
        }
    }
}

#define ACCU(vv) \
    a0 += (float)vv[0]; a1 += (float)vv[1]; a2 += (float)vv[2]; a3 += (float)vv[3]; \
    a4 += (float)vv[4]; a5 += (float)vv[5]; a6 += (float)vv[6]; a7 += (float)vv[7];

// ---------------------------------------------------------------- FUSED gather layer 1 + layer-2 GEMM
// Phase A unchanged (row-major hMsg, plain sum, swizzled LDS tile).
// Phase B: epilogue writes hA PANEL-MAJOR: panel p = feature/16, addr = p*PST + row*16 + (f%16).
// Block 0 also zeroes the 8 per-panel pad entries (node N) — safe here: bukD/bukS are dead,
// and gather_sl (the only pad reader) launches after this kernel completes.
__global__ __launch_bounds__(256) void gather_gemm2(const _Float16* __restrict__ Hh,
                                                    const int* __restrict__ row_ptr,
                                                    const int* __restrict__ col,
                                                    const float* __restrict__ sin_,
                                                    const float* __restrict__ bias,
                                                    const _Float16* __restrict__ Whi,
                                                    const _Float16* __restrict__ Wlo,
                                                    const float* __restrict__ sout,
                                                    _Float16* __restrict__ Y)
{
    __shared__ _Float16 At[16][128];                 // 4 KB layer-1 output tile (swizzled)
    const int tid = threadIdx.x;
    if (blockIdx.x == 0 && tid < 16) {               // zero hA pad entries: 8 panels x 32 B
        int p = tid >> 1, half = tid & 1;
        _Float16* dst = Y + (size_t)p * PST + (size_t)N_NODES * 16 + half * 8;
        *reinterpret_cast<int4*>(dst) = make_int4(0, 0, 0, 0);
    }
    const int sub  = tid & 15;
    const int g0   = tid >> 4;
    const int node = blockIdx.x * 16 + g0;
    const int beg = row_ptr[2 * node], end = row_ptr[2 * node + 1];
    const half8* __restrict__ H8 = reinterpret_cast<const half8*>(Hh);

    float a0 = 0.f, a1 = 0.f, a2 = 0.f, a3 = 0.f, a4 = 0.f, a5 = 0.f, a6 = 0.f, a7 = 0.f;
    int i = beg;
    for (; i + 8 <= end; i += 8) {
        int4 ca = *reinterpret_cast<const int4*>(col + i);
        int4 cb = *reinterpret_cast<const int4*>(col + i + 4);
        half8 v0 = H8[((size_t)ca.x << 4) | sub];
        half8 v1 = H8[((size_t)ca.y << 4) | sub];
        half8 v2 = H8[((size_t)ca.z << 4) | sub];
        half8 v3 = H8[((size_t)ca.w << 4) | sub];
        half8 v4 = H8[((size_t)cb.x << 4) | sub];
        half8 v5 = H8[((size_t)cb.y << 4) | sub];
        half8 v6 = H8[((size_t)cb.z << 4) | sub];
        half8 v7 = H8[((size_t)cb.w << 4) | sub];
        ACCU(v0) ACCU(v1) ACCU(v2) ACCU(v3)
        ACCU(v4) ACCU(v5) ACCU(v6) ACCU(v7)
    }
    if (i < end) {                                   // exactly one padded 4-group
        int4 ca = *reinterpret_cast<const int4*>(col + i);
        half8 v0 = H8[((size_t)ca.x << 4) | sub];
        half8 v1 = H8[((size_t)ca.y << 4) | sub];
        half8 v2 = H8[((size_t)ca.z << 4) | sub];
        half8 v3 = H8[((size_t)ca.w << 4) | sub];
        ACCU(v0) ACCU(v1) ACCU(v2) ACCU(v3)
    }
    {
        float scn = sin_[node];
        const float4* B4 = reinterpret_cast<const float4*>(bias);
        float4 bA = B4[2 * sub], bB = B4[2 * sub + 1];
        half8 o;
        o[0] = (_Float16)fmaxf(fmaf(a0, scn, bA.x), 0.f);
        o[1] = (_Float16)fmaxf(fmaf(a1, scn, bA.y), 0.f);
        o[2] = (_Float16)fmaxf(fmaf(a2, scn, bA.z), 0.f);
        o[3] = (_Float16)fmaxf(fmaf(a3, scn, bA.w), 0.f);
        o[4] = (_Float16)fmaxf(fmaf(a4, scn, bB.x), 0.f);
        o[5] = (_Float16)fmaxf(fmaf(a5, scn, bB.y), 0.f);
        o[6] = (_Float16)fmaxf(fmaf(a6, scn, bB.z), 0.f);
        o[7] = (_Float16)fmaxf(fmaf(a7, scn, bB.w), 0.f);
        int wc = sub ^ (g0 & 7);                       // swizzled 16B-chunk index
        *reinterpret_cast<half8*>(&At[g0][wc * 8]) = o;
    }
    __syncthreads();

    // ---------------- phase B: 16x128 @ 128x128 GEMM (W exact via hi+lo) ----------------
    const int l = tid & 63, w = tid >> 6;
    const int quad = l >> 4, m = l & 15;
    const half8* Bh = reinterpret_cast<const half8*>(Whi);
    const half8* Bl = reinterpret_cast<const half8*>(Wlo);

    f32x4 acc0 = {}, acc1 = {};
    #pragma unroll
    for (int kc = 0; kc < 4; kc++) {
        int rc = (kc * 4 + quad) ^ (m & 7);            // swizzled 16B-chunk index
        half8 a = *reinterpret_cast<const half8*>(&At[m][rc * 8]);
        int f0 = kc * 8 + w * 2;
        half8 bh0 = Bh[f0 * 64 + l];
        half8 bl0 = Bl[f0 * 64 + l];
        half8 bh1 = Bh[(f0 + 1) * 64 + l];
        half8 bl1 = Bl[(f0 + 1) * 64 + l];
        acc0 = __builtin_amdgcn_mfma_f32_16x16x32_f16(a, bh0, acc0, 0, 0, 0);
        acc0 = __builtin_amdgcn_mfma_f32_16x16x32_f16(a, bl0, acc0, 0, 0, 0);
        acc1 = __builtin_amdgcn_mfma_f32_16x16x32_f16(a, bh1, acc1, 0, 0, 0);
        acc1 = __builtin_amdgcn_mfma_f32_16x16x32_f16(a, bl1, acc1, 0, 0, 0);
    }

    // panel-major store: feature c0=(w*2)*16+m -> panel w*2, in-panel feat m; c0+16 -> panel w*2+1
    const int rbase = blockIdx.x * 16 + quad * 4;
    const size_t pb0 = (size_t)(w * 2) * PST;
    const size_t pb1 = pb0 + PST;
    #pragma unroll
    for (int r = 0; r < 4; r++) {
        int grow = rbase + r;
        float s = sout[grow];
        Y[pb0 + (size_t)grow * 16 + m] = (_Float16)(acc0[r] * s);
        Y[pb1 + (size_t)grow * 16 + m] = (_Float16)(acc1[r] * s);
    }
}

// ---------------------------------------------------------------- XCD-sliced gather layer 2
// Grid: 782 groups x 8 slices; slice = bid & 7 (consecutive blocks round-robin XCDs -> panel s resident in XCD s's L2).
// Block: 256 thr = 128 nodes x 2 lanes; lane j covers 8 features of its slice's 16-feature panel.
// Writes h2 panel-major [8][N][16] (contiguous per panel, no cross-XCD line sharing).
__global__ __launch_bounds__(256) void gather_sl(const _Float16* __restrict__ Ha,   // hA panel-major
                                                 const int* __restrict__ row_ptr,
                                                 const int* __restrict__ col,
                                                 const float* __restrict__ sin_,
                                                 const float* __restrict__ bias,
                                                 _Float16* __restrict__ Y2, int N)
{
    const int slice = blockIdx.x & 7;
    const int g     = blockIdx.x >> 3;
    const int j     = threadIdx.x & 1;
    const int node  = g * 128 + (threadIdx.x >> 1);
    if (node >= N) return;
    const int beg = row_ptr[2 * node], end = row_ptr[2 * node + 1];
    const half8* __restrict__ P = reinterpret_cast<const half8*>(Ha + (size_t)slice * PST);
    // entry for row c, half j: element offset c*16 + j*8 -> half8 index c*2 + j

    float a0 = 0.f, a1 = 0.f, a2 = 0.f, a3 = 0.f, a4 = 0.f, a5 = 0.f, a6 = 0.f, a7 = 0.f;
    int i = beg;
    for (; i + 8 <= end; i += 8) {
        int4 ca = *reinterpret_cast<const int4*>(col + i);
        int4 cb = *reinterpret_cast<const int4*>(col + i + 4);
        half8 v0 = P[((size_t)ca.x << 1) | j];
        half8 v1 = P[((size_t)ca.y << 1) | j];
        half8 v2 = P[((size_t)ca.z << 1) | j];
        half8 v3 = P[((size_t)ca.w << 1) | j];
        half8 v4 = P[((size_t)cb.x << 1) | j];
        half8 v5 = P[((size_t)cb.y << 1) | j];
        half8 v6 = P[((size_t)cb.z << 1) | j];
        half8 v7 = P[((size_t)cb.w << 1) | j];
        ACCU(v0) ACCU(v1) ACCU(v2) ACCU(v3)
        ACCU(v4) ACCU(v5) ACCU(v6) ACCU(v7)
    }
    if (i < end) {                                   // exactly one padded 4-group
        int4 ca = *reinterpret_cast<const int4*>(col + i);
        half8 v0 = P[((size_t)ca.x << 1) | j];
        half8 v1 = P[((size_t)ca.y << 1) | j];
        half8 v2 = P[((size_t)ca.z << 1) | j];
        half8 v3 = P[((size_t)ca.w << 1) | j];
        ACCU(v0) ACCU(v1) ACCU(v2) ACCU(v3)
    }
    float scn = sin_[node];
    // bias features [slice*16 + j*8 .. +8) -> float4 index slice*4 + j*2
    const float4* B4 = reinterpret_cast<const float4*>(bias);
    float4 bA = B4[slice * 4 + j * 2], bB = B4[slice * 4 + j * 2 + 1];
    half8 o;
    o[0] = (_Float16)fmaxf(fmaf(a0, scn, bA.x), 0.f);
    o[1] = (_Float16)fmaxf(fmaf(a1, scn, bA.y), 0.f);
    o[2] = (_Float16)fmaxf(fmaf(a2, scn, bA.z), 0.f);
    o[3] = (_Float16)fmaxf(fmaf(a3, scn, bA.w), 0.f);
    o[4] = (_Float16)fmaxf(fmaf(a4, scn, bB.x), 0.f);
    o[5] = (_Float16)fmaxf(fmaf(a5, scn, bB.y), 0.f);
    o[6] = (_Float16)fmaxf(fmaf(a6, scn, bB.z), 0.f);
    o[7] = (_Float16)fmaxf(fmaf(a7, scn, bB.w), 0.f);
    reinterpret_cast<half8*>(Y2)[(size_t)slice * (PS2 / 8) + (size_t)node * 2 + j] = o;
}

// ---------------------------------------------------------------- classifier (panel-major h2 in)
__global__ __launch_bounds__(256) void classifier(const _Float16* __restrict__ H2,
                                                  const float* __restrict__ Wc,
                                                  const float* __restrict__ bc,
                                                  float* __restrict__ out, int N)
{
    __shared__ float4 Wcs[128];   // feature f -> 4 class weights
    for (int t = threadIdx.x; t < 128; t += 256)
        Wcs[t] = reinterpret_cast<const float4*>(Wc)[t];
    __syncthreads();
    int i = blockIdx.x * 256 + threadIdx.x;
    if (i >= N) return;
    float4 acc = reinterpret_cast<const float4*>(bc)[0];
    #pragma unroll
    for (int p = 0; p < 8; p++) {
        const half8* hp = reinterpret_cast<const half8*>(H2 + (size_t)p * PS2 + (size_t)i * 16);
        half8 x0 = hp[0], x1 = hp[1];
        #pragma unroll
        for (int k = 0; k < 8; k++) {
            float f0 = (float)x0[k];
            float4 w0 = Wcs[p * 16 + k];
            acc.x = fmaf(f0, w0.x, acc.x); acc.y = fmaf(f0, w0.y, acc.y);
            acc.z = fmaf(f0, w0.z, acc.z); acc.w = fmaf(f0, w0.w, acc.w);
        }
        #pragma unroll
        for (int k = 0; k < 8; k++) {
            float f1 = (float)x1[k];
            float4 w1 = Wcs[p * 16 + 8 + k];
            acc.x = fmaf(f1, w1.x, acc.x); acc.y = fmaf(f1, w1.y, acc.y);
            acc.z = fmaf(f1, w1.z, acc.z); acc.w = fmaf(f1, w1.w, acc.w);
        }
    }
    reinterpret_cast<float4*>(out)[i] = acc;
}

// ---------------------------------------------------------------- launch
extern "C" void kernel_launch(void* const* d_in, const int* in_sizes, int n_in,
                              void* d_out, int out_size, void* d_ws, size_t ws_size,
                              hipStream_t stream)
{
    const float* features = (const float*)d_in[0];
    const int*   src      = (const int*)d_in[1];
    const int*   dst      = (const int*)d_in[2];
    const float* W1       = (const float*)d_in[3];
    const float* b1       = (const float*)d_in[4];
    const float* W2       = (const float*)d_in[5];
    const float* b2       = (const float*)d_in[6];
    const float* Wc       = (const float*)d_in[7];
    const float* bc       = (const float*)d_in[8];
    float* out = (float*)d_out;

    char* ws = (char*)d_ws;
    const size_t MB = 1 << 20;
    int* curD  = (int*)(ws + 0);                             // NBUK ints
    int* curS  = (int*)(ws + 1024);                          // NBUK ints
    _Float16* Whi1 = (_Float16*)(ws + 64 * 1024);            // 32 KB
    _Float16* Wlo1 = (_Float16*)(ws + 96 * 1024);            // 32 KB
    _Float16* Whi2 = (_Float16*)(ws + 128 * 1024);           // 32 KB
    _Float16* Wlo2 = (_Float16*)(ws + 160 * 1024);           // 32 KB
    float* sout    = (float*)(ws + 512 * 1024);              // N floats (400 KB)
    float* sin_    = (float*)(ws + 1 * MB);                  // N floats
    int*   row_ptr = (int*)(ws + 2 * MB);                    // 2N ints
    int*   col     = (int*)(ws + 3 * MB);                    // NBUK*CAP ints   (7.66 MB) -> ends 10.66
    _Float16* hMsg = (_Float16*)(ws + 25 * MB);              // [N+1,128] fp16 row-major (25.63 MB) -> ends 50.63
    // h2 aliases hMsg: hMsg is dead once gather_gemm2 completes
    _Float16* h2   = (_Float16*)(ws + 25 * MB);              // [8][N][16] fp16 panel-major (25.6 MB)
    // bukD/bukS alias the hA region: dead before gather_gemm2 writes hA
    int*   bukD    = (int*)(ws + 52 * MB);                   // NBUK*CAP ints   (7.66 MB)
    unsigned short* bukS = (unsigned short*)(ws + 60 * MB);  // NBUK*CAP u16    (3.83 MB)
    _Float16* hA   = (_Float16*)(ws + 52 * MB);              // [8][N+1][16] fp16 panel-major (25.63 MB) -> ends 77.66

    const int N = N_NODES;
    const int NGB  = (N + 15) / 16;                          // 6250 fused-gather blocks
    const int NGSL = ((N + 127) / 128) * 8;                  // 782 groups x 8 slices = 6256

    // ---- K1: cursors + hMsg pad row + pack weights (hA pads zeroed later, in gather_gemm2)
    init_pack<<<129, 256, 0, stream>>>(curD, curS, hMsg + (size_t)N * F,
                                       W1, W2, Whi1, Wlo1, Whi2, Wlo2);

    // ---- K2: partition only (784 blocks)
    part_edges<<<NPART, 512, 0, stream>>>(src, dst, curD, curS, bukD, bukS);

    // ---- K3: out-degree -> sout
    deg_out<<<NBUK, 512, 0, stream>>>(bukS, curS, sout);

    // ---- K4: csr + gemm1 (sout folded into hMsg)
    csr_gemm1<<<NBUK + 391, 512, 0, stream>>>(bukD, curD, row_ptr, sin_, col,
                                              features, Whi1, Wlo1, sout, hMsg, N);

    // ---- fused: layer-1 aggregate + layer-2 GEMM -> hA (panel-major; zeroes hA pads first)
    gather_gemm2<<<NGB, 256, 0, stream>>>(hMsg, row_ptr, col, sin_, b1,
                                          Whi2, Wlo2, sout, hA);

    // ---- XCD-sliced layer-2 aggregate -> h2 (panel-major; h2 reuses dead hMsg region)
    gather_sl<<<NGSL, 256, 0, stream>>>(hA, row_ptr, col, sin_, b2, h2, N);

    // ---- classifier (streaming h2 -> out)
    classifier<<<(N + 255) / 256, 256, 0, stream>>>(h2, Wc, bc, out, N);
}

// Round 14
// 284.592 us; speedup vs baseline: 1.1033x; 1.1033x over previous
//
#include <hip/hip_runtime.h>
#include <hip/hip_fp16.h>
#include <math.h>

#define N_NODES 100000
#define N_EDGES 1600000
#define F 128
#define NBUK 196        // ceil(N_NODES / 512)
#define BSH 9           // bucket = node >> 9  (512 nodes per bucket)
#define BSZ 512
#define CAP 10240       // padded bucket capacity (pad-to-4 mean ~8930, sd ~93)
#define NPART 784       // partition blocks (chunk 2044 -> exactly 1 int4 group/thread)

typedef _Float16 half8 __attribute__((ext_vector_type(8)));
typedef float    f32x4 __attribute__((ext_vector_type(4)));
typedef int      i32x4 __attribute__((ext_vector_type(4)));

// ---------------------------------------------------------------- K1: cursors + pad rows + pack W1/W2
// blocks: 0 = cursors/pads, 1..128 = weight pack
__global__ __launch_bounds__(256) void init_pack(int* __restrict__ curD,
                                                 int* __restrict__ curS,
                                                 _Float16* __restrict__ padrow1,   // hMsg + N*F
                                                 _Float16* __restrict__ padrow2,   // hA   + N*F
                                                 const float* __restrict__ W1,
                                                 const float* __restrict__ W2,
                                                 _Float16* __restrict__ hi1,
                                                 _Float16* __restrict__ lo1,
                                                 _Float16* __restrict__ hi2,
                                                 _Float16* __restrict__ lo2)
{
    int t = threadIdx.x;
    if (blockIdx.x == 0) {
        if (t < NBUK) { curD[t] = t * CAP; curS[t] = t * CAP; }
        if (t < 16) reinterpret_cast<int4*>(padrow1)[t] = make_int4(0, 0, 0, 0);
        else if (t >= 32 && t < 48) reinterpret_cast<int4*>(padrow2)[t - 32] = make_int4(0, 0, 0, 0);
        return;
    }
    int gidx = (blockIdx.x - 1) * 256 + t;
    const float* W = (gidx < 16384) ? W1 : W2;
    _Float16* hi = (gidx < 16384) ? hi1 : hi2;
    _Float16* lo = (gidx < 16384) ? lo1 : lo2;
    int idx = gidx & 16383;
    int f = idx >> 9, r = idx & 511;
    int l = r >> 3, j = r & 7;
    int kc = f >> 3, ct = f & 7;
    int k = kc * 32 + (l >> 4) * 8 + j;
    int n = ct * 16 + (l & 15);
    float w = W[k * 128 + n];
    _Float16 h = (_Float16)w;
    hi[idx] = h;
    lo[idx] = (_Float16)(w - (float)h);
}

// ---------------------------------------------------------------- K2: partition only (784 blocks, 1 int4 group/thread,
// edges held in registers across both phases)
__global__ __launch_bounds__(512) void part_edges(const int* __restrict__ src,
                                                  const int* __restrict__ dst,
                                                  int* __restrict__ curD,
                                                  int* __restrict__ curS,
                                                  int* __restrict__ bukD,
                                                  unsigned short* __restrict__ bukS)
{
    __shared__ int hd[NBUK], hs[NBUK], bd[NBUK], bs[NBUK], cd[NBUK], cs[NBUK];
    const int tid = threadIdx.x;
    const int chunk = (((N_EDGES + NPART - 1) / NPART) + 3) & ~3;   // 2044
    const int beg = blockIdx.x * chunk;
    const int end = min(beg + chunk, N_EDGES);
    if (beg >= end) return;
    if (tid < NBUK) { hd[tid] = 0; hs[tid] = 0; cd[tid] = 0; cs[tid] = 0; }
    __syncthreads();
    const int b4 = beg >> 2, e4 = end >> 2;
    const int i0 = b4 + tid;                       // exactly <=1 int4 group per thread
    const bool v0 = i0 < e4;
    i32x4 d0 = {}, s0 = {};
    if (v0) {
        d0 = reinterpret_cast<const i32x4*>(dst)[i0];
        s0 = reinterpret_cast<const i32x4*>(src)[i0];
        atomicAdd(&hd[d0.x >> BSH], 1); atomicAdd(&hd[d0.y >> BSH], 1);
        atomicAdd(&hd[d0.z >> BSH], 1); atomicAdd(&hd[d0.w >> BSH], 1);
        atomicAdd(&hs[s0.x >> BSH], 1); atomicAdd(&hs[s0.y >> BSH], 1);
        atomicAdd(&hs[s0.z >> BSH], 1); atomicAdd(&hs[s0.w >> BSH], 1);
    }
    __syncthreads();
    if (tid < NBUK) {
        bd[tid] = hd[tid] ? atomicAdd(&curD[tid], hd[tid]) : 0;
        bs[tid] = hs[tid] ? atomicAdd(&curS[tid], hs[tid]) : 0;
    }
    __syncthreads();
    if (v0) {
        int dd[4] = { d0.x, d0.y, d0.z, d0.w };
        int ss[4] = { s0.x, s0.y, s0.z, s0.w };
        #pragma unroll
        for (int j = 0; j < 4; j++) {
            int bin = dd[j] >> BSH;
            int r = atomicAdd(&cd[bin], 1);
            bukD[bd[bin] + r] = ((dd[j] & 511) << 17) | ss[j];
            int bin2 = ss[j] >> BSH;
            int r2 = atomicAdd(&cs[bin2], 1);
            bukS[bs[bin2] + r2] = (unsigned short)(ss[j] & 511);
        }
    }
}

// ---------------------------------------------------------------- K3: out-degree -> sout (196 blocks, uint4 = 8 entries/load)
__global__ __launch_bounds__(512) void deg_out(const unsigned short* __restrict__ bukS,
                                               const int* __restrict__ curS,
                                               float* __restrict__ sout)
{
    __shared__ int h[BSZ];
    const int tid = threadIdx.x;
    const int n0 = blockIdx.x << BSH;
    const int lo = blockIdx.x * CAP, hi = curS[blockIdx.x];
    const int cnt = hi - lo;
    h[tid] = 0;
    __syncthreads();
    const uint4* p8 = reinterpret_cast<const uint4*>(bukS + lo);   // 16B-aligned (CAP*2 % 16 == 0)
    const int nv = cnt >> 3;
    for (int j = tid; j < nv; j += 512) {
        uint4 v = p8[j];
        atomicAdd(&h[v.x & 0xFFFF], 1); atomicAdd(&h[v.x >> 16], 1);
        atomicAdd(&h[v.y & 0xFFFF], 1); atomicAdd(&h[v.y >> 16], 1);
        atomicAdd(&h[v.z & 0xFFFF], 1); atomicAdd(&h[v.z >> 16], 1);
        atomicAdd(&h[v.w & 0xFFFF], 1); atomicAdd(&h[v.w >> 16], 1);
    }
    for (int i = lo + (nv << 3) + tid; i < hi; i += 512)
        atomicAdd(&h[bukS[i]], 1);
    __syncthreads();
    int node = n0 + tid;
    if (node < N_NODES) sout[node] = rsqrtf((float)max(h[tid], 1));
}

// ---------------------------------------------------------------- K4: csr (196 blocks, col only) + gemm1 scaled by sout (391 blocks)
__global__ __launch_bounds__(512) void csr_gemm1(const int* __restrict__ bukD,
                                                 const int* __restrict__ curD,
                                                 int* __restrict__ row_ptr,
                                                 float* __restrict__ sin_,
                                                 int* __restrict__ col,
                                                 const float* __restrict__ X,
                                                 const _Float16* __restrict__ Whi,
                                                 const _Float16* __restrict__ Wlo,
                                                 const float* __restrict__ sout,
                                                 _Float16* __restrict__ Y, int N)
{
    __shared__ int h[BSZ], sc[BSZ], cur[BSZ];
    const int tid = threadIdx.x;

    if (blockIdx.x < NBUK) {
        const int n0 = blockIdx.x << BSH;
        const int lo = blockIdx.x * CAP, hi = curD[blockIdx.x];
        const int cnt = hi - lo;
        h[tid] = 0;
        __syncthreads();
        const i32x4* p4 = reinterpret_cast<const i32x4*>(bukD + lo);   // 16B-aligned (CAP % 4 == 0)
        const int nv = cnt >> 2;
        for (int j = tid; j < nv; j += 512) {
            i32x4 v = p4[j];
            atomicAdd(&h[((unsigned)v.x) >> 17], 1);
            atomicAdd(&h[((unsigned)v.y) >> 17], 1);
            atomicAdd(&h[((unsigned)v.z) >> 17], 1);
            atomicAdd(&h[((unsigned)v.w) >> 17], 1);
        }
        for (int i = lo + (nv << 2) + tid; i < hi; i += 512)
            atomicAdd(&h[((unsigned)bukD[i]) >> 17], 1);
        __syncthreads();
        int own = h[tid];
        int own4 = (own + 3) & ~3;
        sc[tid] = own4;
        __syncthreads();
        for (int off = 1; off < 512; off <<= 1) {
            int u = (tid >= off) ? sc[tid - off] : 0;
            __syncthreads();
            sc[tid] += u;
            __syncthreads();
        }
        int ex = sc[tid] - own4;
        cur[tid] = ex;
        int node = n0 + tid;
        if (node < N_NODES) {
            row_ptr[2 * node]     = lo + ex;
            row_ptr[2 * node + 1] = lo + ex + own4;          // padded end
            sin_[node] = rsqrtf((float)max(own, 1));
        }
        __syncthreads();
        for (int j = tid; j < nv; j += 512) {
            i32x4 v = p4[j];
            int pv[4] = { v.x, v.y, v.z, v.w };
            #pragma unroll
            for (int q = 0; q < 4; q++) {
                int p = pv[q];
                int r = atomicAdd(&cur[((unsigned)p) >> 17], 1);
                col[lo + r] = p & 0x1FFFF;
            }
        }
        for (int i = lo + (nv << 2) + tid; i < hi; i += 512) {
            int p = bukD[i];
            int r = atomicAdd(&cur[((unsigned)p) >> 17], 1);
            col[lo + r] = p & 0x1FFFF;
        }
        for (int k = own; k < own4; k++)
            col[lo + ex + k] = N_NODES;   // zero row of hMsg
        return;
    }

    // ---------------- gemm1: 512 thr = 8 waves x 32 rows = 256 rows/block, sout-folded output ----------------
    const int l = tid & 63, w = tid >> 6;
    const int quad = l >> 4, m = l & 15;
    const int row0 = (blockIdx.x - NBUK) * 256;
    const half8* Bh = reinterpret_cast<const half8*>(Whi);
    const half8* Bl = reinterpret_cast<const half8*>(Wlo);

    f32x4 acc[2][8] = {};

    for (int kc = 0; kc < 4; kc++) {
        half8 ah[2];
        #pragma unroll
        for (int rt = 0; rt < 2; rt++) {
            int grow = row0 + w * 32 + rt * 16 + m;
            float4 xa = make_float4(0.f, 0.f, 0.f, 0.f), xb = xa;
            if (grow < N) {
                const float4* Xp = reinterpret_cast<const float4*>(X) + (size_t)grow * 32 + kc * 8 + quad * 2;
                xa = Xp[0]; xb = Xp[1];
            }
            ah[rt][0] = (_Float16)xa.x; ah[rt][1] = (_Float16)xa.y;
            ah[rt][2] = (_Float16)xa.z; ah[rt][3] = (_Float16)xa.w;
            ah[rt][4] = (_Float16)xb.x; ah[rt][5] = (_Float16)xb.y;
            ah[rt][6] = (_Float16)xb.z; ah[rt][7] = (_Float16)xb.w;
        }
        #pragma unroll
        for (int ct = 0; ct < 8; ct++) {
            int f = kc * 8 + ct;
            half8 bh = Bh[f * 64 + l];
            half8 bl = Bl[f * 64 + l];
            #pragma unroll
            for (int rt = 0; rt < 2; rt++) {
                acc[rt][ct] = __builtin_amdgcn_mfma_f32_16x16x32_f16(ah[rt], bh, acc[rt][ct], 0, 0, 0);
                acc[rt][ct] = __builtin_amdgcn_mfma_f32_16x16x32_f16(ah[rt], bl, acc[rt][ct], 0, 0, 0);
            }
        }
    }

    #pragma unroll
    for (int rt = 0; rt < 2; rt++) {
        #pragma unroll
        for (int r = 0; r < 4; r++) {
            int grow = row0 + w * 32 + rt * 16 + quad * 4 + r;
            if (grow < N) {
                float s = sout[grow];          // fold edge scale into the message row
                #pragma unroll
                for (int ct = 0; ct < 8; ct++)
                    Y[(size_t)grow * 128 + ct * 16 + m] = (_Float16)(acc[rt][ct][r] * s);
            }
        }
    }
}

#define ACCU(vv) \
    a0 += (float)vv[0]; a1 += (float)vv[1]; a2 += (float)vv[2]; a3 += (float)vv[3]; \
    a4 += (float)vv[4]; a5 += (float)vv[5]; a6 += (float)vv[6]; a7 += (float)vv[7];

// ---------------------------------------------------------------- FUSED gather layer 1 + layer-2 GEMM
// hMsg rows are pre-scaled by sout -> phase A is a plain sum (no wv).
// Phase B: 4 waves do the 16-row x 128x128 MFMA GEMM (A from swizzled LDS), scale by sout -> hA.
__global__ __launch_bounds__(256) void gather_gemm2(const _Float16* __restrict__ Hh,
                                                    const int* __restrict__ row_ptr,
                                                    const int* __restrict__ col,
                                                    const float* __restrict__ sin_,
                                                    const float* __restrict__ bias,
                                                    const _Float16* __restrict__ Whi,
                                                    const _Float16* __restrict__ Wlo,
                                                    const float* __restrict__ sout,
                                                    _Float16* __restrict__ Y)
{
    __shared__ _Float16 At[16][128];                 // 4 KB layer-1 output tile (swizzled)
    const int tid = threadIdx.x;
    const int sub  = tid & 15;
    const int g0   = tid >> 4;
    const int node = blockIdx.x * 16 + g0;
    const int beg = row_ptr[2 * node], end = row_ptr[2 * node + 1];
    const half8* __restrict__ H8 = reinterpret_cast<const half8*>(Hh);

    float a0 = 0.f, a1 = 0.f, a2 = 0.f, a3 = 0.f, a4 = 0.f, a5 = 0.f, a6 = 0.f, a7 = 0.f;
    int i = beg;
    for (; i + 8 <= end; i += 8) {
        int4 ca = *reinterpret_cast<const int4*>(col + i);
        int4 cb = *reinterpret_cast<const int4*>(col + i + 4);
        half8 v0 = H8[((size_t)ca.x << 4) | sub];
        half8 v1 = H8[((size_t)ca.y << 4) | sub];
        half8 v2 = H8[((size_t)ca.z << 4) | sub];
        half8 v3 = H8[((size_t)ca.w << 4) | sub];
        half8 v4 = H8[((size_t)cb.x << 4) | sub];
        half8 v5 = H8[((size_t)cb.y << 4) | sub];
        half8 v6 = H8[((size_t)cb.z << 4) | sub];
        half8 v7 = H8[((size_t)cb.w << 4) | sub];
        ACCU(v0) ACCU(v1) ACCU(v2) ACCU(v3)
        ACCU(v4) ACCU(v5) ACCU(v6) ACCU(v7)
    }
    if (i < end) {                                   // exactly one padded 4-group
        int4 ca = *reinterpret_cast<const int4*>(col + i);
        half8 v0 = H8[((size_t)ca.x << 4) | sub];
        half8 v1 = H8[((size_t)ca.y << 4) | sub];
        half8 v2 = H8[((size_t)ca.z << 4) | sub];
        half8 v3 = H8[((size_t)ca.w << 4) | sub];
        ACCU(v0) ACCU(v1) ACCU(v2) ACCU(v3)
    }
    {
        float scn = sin_[node];
        const float4* B4 = reinterpret_cast<const float4*>(bias);
        float4 bA = B4[2 * sub], bB = B4[2 * sub + 1];
        half8 o;
        o[0] = (_Float16)fmaxf(fmaf(a0, scn, bA.x), 0.f);
        o[1] = (_Float16)fmaxf(fmaf(a1, scn, bA.y), 0.f);
        o[2] = (_Float16)fmaxf(fmaf(a2, scn, bA.z), 0.f);
        o[3] = (_Float16)fmaxf(fmaf(a3, scn, bA.w), 0.f);
        o[4] = (_Float16)fmaxf(fmaf(a4, scn, bB.x), 0.f);
        o[5] = (_Float16)fmaxf(fmaf(a5, scn, bB.y), 0.f);
        o[6] = (_Float16)fmaxf(fmaf(a6, scn, bB.z), 0.f);
        o[7] = (_Float16)fmaxf(fmaf(a7, scn, bB.w), 0.f);
        int wc = sub ^ (g0 & 7);                       // swizzled 16B-chunk index
        *reinterpret_cast<half8*>(&At[g0][wc * 8]) = o;
    }
    __syncthreads();

    // ---------------- phase B: 16x128 @ 128x128 GEMM (W exact via hi+lo) ----------------
    const int l = tid & 63, w = tid >> 6;
    const int quad = l >> 4, m = l & 15;
    const half8* Bh = reinterpret_cast<const half8*>(Whi);
    const half8* Bl = reinterpret_cast<const half8*>(Wlo);

    f32x4 acc0 = {}, acc1 = {};
    #pragma unroll
    for (int kc = 0; kc < 4; kc++) {
        int rc = (kc * 4 + quad) ^ (m & 7);            // swizzled 16B-chunk index
        half8 a = *reinterpret_cast<const half8*>(&At[m][rc * 8]);
        int f0 = kc * 8 + w * 2;
        half8 bh0 = Bh[f0 * 64 + l];
        half8 bl0 = Bl[f0 * 64 + l];
        half8 bh1 = Bh[(f0 + 1) * 64 + l];
        half8 bl1 = Bl[(f0 + 1) * 64 + l];
        acc0 = __builtin_amdgcn_mfma_f32_16x16x32_f16(a, bh0, acc0, 0, 0, 0);
        acc0 = __builtin_amdgcn_mfma_f32_16x16x32_f16(a, bl0, acc0, 0, 0, 0);
        acc1 = __builtin_amdgcn_mfma_f32_16x16x32_f16(a, bh1, acc1, 0, 0, 0);
        acc1 = __builtin_amdgcn_mfma_f32_16x16x32_f16(a, bl1, acc1, 0, 0, 0);
    }

    const int rbase = blockIdx.x * 16 + quad * 4;
    const int c0 = (w * 2) * 16 + m;
    #pragma unroll
    for (int r = 0; r < 4; r++) {
        int grow = rbase + r;
        float s = sout[grow];
        Y[(size_t)grow * 128 + c0]      = (_Float16)(acc0[r] * s);
        Y[(size_t)grow * 128 + c0 + 16] = (_Float16)(acc1[r] * s);
    }
}

// ---------------------------------------------------------------- gather layer 2 + fused classifier
__global__ __launch_bounds__(256) void gather_cls(const _Float16* __restrict__ Hh,
                                                  const int* __restrict__ row_ptr,
                                                  const int* __restrict__ col,
                                                  const float* __restrict__ sin_,
                                                  const float* __restrict__ bias,
                                                  const float* __restrict__ Wc,
                                                  const float* __restrict__ bc,
                                                  float* __restrict__ out, int N)
{
    __shared__ float4 Wcs[128];
    for (int t = threadIdx.x; t < 128; t += 256)
        Wcs[t] = reinterpret_cast<const float4*>(Wc)[t];
    __syncthreads();

    const int sub  = threadIdx.x & 15;
    const int node = blockIdx.x * 16 + (threadIdx.x >> 4);
    if (node >= N) return;
    const int beg = row_ptr[2 * node], end = row_ptr[2 * node + 1];
    const half8* __restrict__ H8 = reinterpret_cast<const half8*>(Hh);

    float a0 = 0.f, a1 = 0.f, a2 = 0.f, a3 = 0.f, a4 = 0.f, a5 = 0.f, a6 = 0.f, a7 = 0.f;
    int i = beg;
    for (; i + 8 <= end; i += 8) {
        int4 ca = *reinterpret_cast<const int4*>(col + i);
        int4 cb = *reinterpret_cast<const int4*>(col + i + 4);
        half8 v0 = H8[((size_t)ca.x << 4) | sub];
        half8 v1 = H8[((size_t)ca.y << 4) | sub];
        half8 v2 = H8[((size_t)ca.z << 4) | sub];
        half8 v3 = H8[((size_t)ca.w << 4) | sub];
        half8 v4 = H8[((size_t)cb.x << 4) | sub];
        half8 v5 = H8[((size_t)cb.y << 4) | sub];
        half8 v6 = H8[((size_t)cb.z << 4) | sub];
        half8 v7 = H8[((size_t)cb.w << 4) | sub];
        ACCU(v0) ACCU(v1) ACCU(v2) ACCU(v3)
        ACCU(v4) ACCU(v5) ACCU(v6) ACCU(v7)
    }
    if (i < end) {
        int4 ca = *reinterpret_cast<const int4*>(col + i);
        half8 v0 = H8[((size_t)ca.x << 4) | sub];
        half8 v1 = H8[((size_t)ca.y << 4) | sub];
        half8 v2 = H8[((size_t)ca.z << 4) | sub];
        half8 v3 = H8[((size_t)ca.w << 4) | sub];
        ACCU(v0) ACCU(v1) ACCU(v2) ACCU(v3)
    }
    float scn = sin_[node];
    const float4* B4 = reinterpret_cast<const float4*>(bias);
    float4 bA = B4[2 * sub], bB = B4[2 * sub + 1];
    float h0 = fmaxf(fmaf(a0, scn, bA.x), 0.f);
    float h1 = fmaxf(fmaf(a1, scn, bA.y), 0.f);
    float h2 = fmaxf(fmaf(a2, scn, bA.z), 0.f);
    float h3 = fmaxf(fmaf(a3, scn, bA.w), 0.f);
    float h4 = fmaxf(fmaf(a4, scn, bB.x), 0.f);
    float h5 = fmaxf(fmaf(a5, scn, bB.y), 0.f);
    float h6 = fmaxf(fmaf(a6, scn, bB.z), 0.f);
    float h7 = fmaxf(fmaf(a7, scn, bB.w), 0.f);

    float lx = 0.f, ly = 0.f, lz = 0.f, lw = 0.f;
    float4 w;
    w = Wcs[sub * 8 + 0]; lx = fmaf(h0, w.x, lx); ly = fmaf(h0, w.y, ly); lz = fmaf(h0, w.z, lz); lw = fmaf(h0, w.w, lw);
    w = Wcs[sub * 8 + 1]; lx = fmaf(h1, w.x, lx); ly = fmaf(h1, w.y, ly); lz = fmaf(h1, w.z, lz); lw = fmaf(h1, w.w, lw);
    w = Wcs[sub * 8 + 2]; lx = fmaf(h2, w.x, lx); ly = fmaf(h2, w.y, ly); lz = fmaf(h2, w.z, lz); lw = fmaf(h2, w.w, lw);
    w = Wcs[sub * 8 + 3]; lx = fmaf(h3, w.x, lx); ly = fmaf(h3, w.y, ly); lz = fmaf(h3, w.z, lz); lw = fmaf(h3, w.w, lw);
    w = Wcs[sub * 8 + 4]; lx = fmaf(h4, w.x, lx); ly = fmaf(h4, w.y, ly); lz = fmaf(h4, w.z, lz); lw = fmaf(h4, w.w, lw);
    w = Wcs[sub * 8 + 5]; lx = fmaf(h5, w.x, lx); ly = fmaf(h5, w.y, ly); lz = fmaf(h5, w.z, lz); lw = fmaf(h5, w.w, lw);
    w = Wcs[sub * 8 + 6]; lx = fmaf(h6, w.x, lx); ly = fmaf(h6, w.y, ly); lz = fmaf(h6, w.z, lz); lw = fmaf(h6, w.w, lw);
    w = Wcs[sub * 8 + 7]; lx = fmaf(h7, w.x, lx); ly = fmaf(h7, w.y, ly); lz = fmaf(h7, w.z, lz); lw = fmaf(h7, w.w, lw);

    #pragma unroll
    for (int m = 1; m < 16; m <<= 1) {
        lx += __shfl_xor(lx, m);
        ly += __shfl_xor(ly, m);
        lz += __shfl_xor(lz, m);
        lw += __shfl_xor(lw, m);
    }
    if (sub == 0) {
        float4 bcv = reinterpret_cast<const float4*>(bc)[0];
        float4 r;
        r.x = lx + bcv.x; r.y = ly + bcv.y; r.z = lz + bcv.z; r.w = lw + bcv.w;
        reinterpret_cast<float4*>(out)[node] = r;
    }
}

// ---------------------------------------------------------------- launch
extern "C" void kernel_launch(void* const* d_in, const int* in_sizes, int n_in,
                              void* d_out, int out_size, void* d_ws, size_t ws_size,
                              hipStream_t stream)
{
    const float* features = (const float*)d_in[0];
    const int*   src      = (const int*)d_in[1];
    const int*   dst      = (const int*)d_in[2];
    const float* W1       = (const float*)d_in[3];
    const float* b1       = (const float*)d_in[4];
    const float* W2       = (const float*)d_in[5];
    const float* b2       = (const float*)d_in[6];
    const float* Wc       = (const float*)d_in[7];
    const float* bc       = (const float*)d_in[8];
    float* out = (float*)d_out;

    char* ws = (char*)d_ws;
    const size_t MB = 1 << 20;
    int* curD  = (int*)(ws + 0);                             // NBUK ints
    int* curS  = (int*)(ws + 1024);                          // NBUK ints
    _Float16* Whi1 = (_Float16*)(ws + 64 * 1024);            // 32 KB
    _Float16* Wlo1 = (_Float16*)(ws + 96 * 1024);            // 32 KB
    _Float16* Whi2 = (_Float16*)(ws + 128 * 1024);           // 32 KB
    _Float16* Wlo2 = (_Float16*)(ws + 160 * 1024);           // 32 KB
    float* sout    = (float*)(ws + 512 * 1024);              // N floats (400 KB)
    float* sin_    = (float*)(ws + 1 * MB);                  // N floats
    int*   row_ptr = (int*)(ws + 2 * MB);                    // 2N ints
    int*   col     = (int*)(ws + 3 * MB);                    // NBUK*CAP ints   (7.66 MB) -> ends 10.66
    _Float16* hMsg = (_Float16*)(ws + 25 * MB);              // [N+1,128] fp16 row-major (25.63 MB) -> ends 50.63
    // bukD/bukS alias the hA region: dead (after csr_gemm1 / deg_out) before gather_gemm2 writes hA
    int*   bukD    = (int*)(ws + 52 * MB);                   // NBUK*CAP ints   (7.66 MB)
    unsigned short* bukS = (unsigned short*)(ws + 60 * MB);  // NBUK*CAP u16    (3.83 MB)
    _Float16* hA   = (_Float16*)(ws + 52 * MB);              // [N+1,128] fp16 (25.63 MB) -> ends 77.66

    const int N = N_NODES;
    const int NGB = (N + 15) / 16;                           // 6250 gather blocks (16 nodes each)

    // ---- K1: cursors + pad rows (hMsg and hA) + pack weights
    init_pack<<<129, 256, 0, stream>>>(curD, curS,
                                       hMsg + (size_t)N * F, hA + (size_t)N * F,
                                       W1, W2, Whi1, Wlo1, Whi2, Wlo2);

    // ---- K2: partition only (784 blocks, all CUs)
    part_edges<<<NPART, 512, 0, stream>>>(src, dst, curD, curS, bukD, bukS);

    // ---- K3: out-degree -> sout
    deg_out<<<NBUK, 512, 0, stream>>>(bukS, curS, sout);

    // ---- K4: csr (col/row_ptr/sin_, no wv) + gemm1 with sout folded into hMsg
    csr_gemm1<<<NBUK + 391, 512, 0, stream>>>(bukD, curD, row_ptr, sin_, col,
                                              features, Whi1, Wlo1, sout, hMsg, N);

    // ---- fused: layer-1 aggregate (plain sum) + layer-2 GEMM -> hA
    gather_gemm2<<<NGB, 256, 0, stream>>>(hMsg, row_ptr, col, sin_, b1,
                                          Whi2, Wlo2, sout, hA);

    // ---- layer-2 aggregate + classifier (reads hA)
    gather_cls<<<NGB, 256, 0, stream>>>(hA, row_ptr, col, sin_, b2, Wc, bc, out, N);
}